// Round 1
// 685.303 us; speedup vs baseline: 1.1530x; 1.1530x over previous
//
#include <hip/hip_runtime.h>

typedef unsigned int u32;
typedef unsigned short u16;
typedef __attribute__((ext_vector_type(8))) short bf16x8;
typedef __attribute__((ext_vector_type(4))) float f32x4;

#define Bb 4
#define Nn 50000
#define Dd 128
#define Rr 200
#define BN (Bb*Nn)
#define MAXDEG 32
#define LDW 136          // u16 row stride inside a wave slab (272 B, 16B-aligned)
#define SLAB 4352        // u16 per wave slab: 2 tiles x 16 rows x 136

// ---------- scalar helpers ----------
__device__ __forceinline__ float bfs(u16 u) { return __uint_as_float(((u32)u) << 16); }
__device__ __forceinline__ float bflo(u32 u) { return __uint_as_float(u << 16); }
__device__ __forceinline__ float bfhi(u32 u) { return __uint_as_float(u & 0xffff0000u); }
__device__ __forceinline__ u16 f2bf(float f) {
    u32 x = __float_as_uint(f);
    return (u16)((x + 0x7fffu + ((x >> 16) & 1u)) >> 16);
}
template<bool BF>
__device__ __forceinline__ float ld1(const void* p, int i) {
    if (BF) return bfs(((const u16*)p)[i]);
    else    return ((const float*)p)[i];
}

// ---------- dtype probe: bf16-packed vs f32 ----------
__global__ void k_probe(const u32* __restrict__ q, int* __restrict__ flag) {
    int t = threadIdx.x;
    u32 w = q[t];
    int e = (int)((w >> 7) & 0xffu);
    bool plaus = (e >= 100 && e <= 150);
    unsigned long long m = __ballot(plaus);
    if (t == 0) flag[0] = (__popcll(m) >= 56) ? 1 : 0;
}

// ---------- prep: split weights to bf16 hi/lo, f32 copies of small tensors ----------
__global__ __launch_bounds__(256) void k_wprep(
    const void* Ws, const void* w1, const void* w2,
    const void* b1, const void* b2, const void* wattn, const void* rela,
    u16* WsH, u16* WsL, u16* w1H, u16* w1L, u16* w2H, u16* w2L,
    float* b1f, float* b2f, float* wattnf, float* relaf, const int* flag) {
    bool bf = (*flag != 0);
    int i = blockIdx.x * 256 + threadIdx.x;
    if (i < 16384) {
        float x = bf ? bfs(((const u16*)Ws)[i]) : ((const float*)Ws)[i];
        u16 h = f2bf(x); WsH[i] = h; WsL[i] = f2bf(x - bfs(h));
    } else if (i < 32768) {
        int j = i - 16384;
        float x = bf ? bfs(((const u16*)w1)[j]) : ((const float*)w1)[j];
        u16 h = f2bf(x); w1H[j] = h; w1L[j] = f2bf(x - bfs(h));
    } else if (i < 49152) {
        int j = i - 32768;
        float x = bf ? bfs(((const u16*)w2)[j]) : ((const float*)w2)[j];
        u16 h = f2bf(x); w2H[j] = h; w2L[j] = f2bf(x - bfs(h));
    } else if (i < 49152 + 128) {
        int j = i - 49152;
        b1f[j] = bf ? bfs(((const u16*)b1)[j]) : ((const float*)b1)[j];
    } else if (i < 49152 + 256) {
        int j = i - 49152 - 128;
        b2f[j] = bf ? bfs(((const u16*)b2)[j]) : ((const float*)b2)[j];
    } else if (i < 49152 + 384) {
        int j = i - 49152 - 256;
        wattnf[j] = bf ? bfs(((const u16*)wattn)[j]) : ((const float*)wattn)[j];
    } else if (i < 49152 + 384 + 25600) {
        int j = i - 49152 - 384;
        relaf[j] = bf ? bfs(((const u16*)rela)[j]) : ((const float*)rela)[j];
    }
}

// ---------- wrq[b*R+r][a] = Wr.rela_r + Wqr.query_b + bias (tiny, f32 VALU) ----------
template<bool BF>
__device__ __forceinline__ float dotrow1(const void* W, int row, const float* s) {
    float acc = 0.f;
    if (BF) {
        const uint4* wv = (const uint4*)((const u16*)W + row * Dd);
#pragma unroll
        for (int k = 0; k < 16; k++) {
            uint4 u = wv[k];
            acc += bflo(u.x)*s[k*8+0] + bfhi(u.x)*s[k*8+1]
                 + bflo(u.y)*s[k*8+2] + bfhi(u.y)*s[k*8+3]
                 + bflo(u.z)*s[k*8+4] + bfhi(u.z)*s[k*8+5]
                 + bflo(u.w)*s[k*8+6] + bfhi(u.w)*s[k*8+7];
        }
    } else {
        const float4* wv = (const float4*)((const float*)W + row * Dd);
#pragma unroll
        for (int k = 0; k < 32; k++) {
            float4 u = wv[k];
            acc += u.x*s[4*k] + u.y*s[4*k+1] + u.z*s[4*k+2] + u.w*s[4*k+3];
        }
    }
    return acc;
}
template<bool BF>
__device__ void k_wrq_body(const void* Wr, const void* Wqr, const void* bias,
                           const void* rela, const void* query, float* wrq, float* s) {
    int br = blockIdx.x;
    int b = br / Rr, r = br % Rr;
    int a = threadIdx.x;
    s[a]      = ld1<BF>(rela,  r * Dd + a);
    s[Dd + a] = ld1<BF>(query, b * Dd + a);
    __syncthreads();
    wrq[br * Dd + a] = ld1<BF>(bias, a) + dotrow1<BF>(Wr, a, s) + dotrow1<BF>(Wqr, a, s + Dd);
}
__global__ __launch_bounds__(128) void k_wrq(const void* Wr, const void* Wqr, const void* bias,
                                             const void* rela, const void* query, float* wrq,
                                             const int* flag) {
    __shared__ float s[2 * Dd];
    if (*flag) k_wrq_body<true>(Wr, Wqr, bias, rela, query, wrq, s);
    else       k_wrq_body<false>(Wr, Wqr, bias, rela, query, wrq, s);
}

// ---------- hs = hidden @ Ws^T via split-bf16 MFMA (wave-private slab, no barriers) ----------
// NOTE: the __shared__ slab lives in the __global__ wrapper, NOT in this template body.
// With the declaration inside the template, both <true>/<false> instantiations each got
// their own 34816B static LDS allocation (LDS_Block_Size=69632 -> 2 blocks/CU).
template<bool BF>
__device__ void hs_body(const void* hidden, const u16* WsH, const u16* WsL, u16* hs,
                        u16* __restrict__ Smh) {
    int t = threadIdx.x, lane = t & 63;
    int m16 = lane & 15, quad = lane >> 4;
    int w = t >> 6;
    int base = blockIdx.x * 64 + w * 16;
    u16* Sml = Smh + 16 * LDW;

    if (BF) {
        const u16* src = (const u16*)hidden + (size_t)base * Dd;
#pragma unroll
        for (int j = 0; j < 4; j++) {
            int flat = j * 64 + lane;            // 256 chunks of 8 u16
            int row = flat >> 4, c8 = (flat & 15) * 8;
            uint4 v = ((const uint4*)src)[flat];
            *(uint4*)(Smh + row * LDW + c8) = v;
        }
    } else {
        const float* src = (const float*)hidden + (size_t)base * Dd;
#pragma unroll
        for (int j = 0; j < 8; j++) {
            int flat = j * 64 + lane;            // 512 float4 chunks
            int row = flat >> 5, c4 = (flat & 31) * 4;
            float4 v = ((const float4*)src)[flat];
            u16 h0 = f2bf(v.x), h1 = f2bf(v.y), h2 = f2bf(v.z), h3 = f2bf(v.w);
            ushort4 hv; hv.x = h0; hv.y = h1; hv.z = h2; hv.w = h3;
            ushort4 lv; lv.x = f2bf(v.x - bfs(h0)); lv.y = f2bf(v.y - bfs(h1));
                        lv.z = f2bf(v.z - bfs(h2)); lv.w = f2bf(v.w - bfs(h3));
            *(ushort4*)(Smh + row * LDW + c4) = hv;
            *(ushort4*)(Sml + row * LDW + c4) = lv;
        }
    }
    // frags (same-wave RAW on LDS; compiler inserts lgkmcnt)
    const u16* ph = Smh + m16 * LDW + quad * 8;
    const u16* pl = Sml + m16 * LDW + quad * 8;
    bf16x8 ah[4], al[4];
#pragma unroll
    for (int ks = 0; ks < 4; ks++) {
        ah[ks] = *(const bf16x8*)(ph + ks * 32);
        if (!BF) al[ks] = *(const bf16x8*)(pl + ks * 32);
    }
#pragma unroll
    for (int nt = 0; nt < 8; nt++) {
        int n = nt * 16 + m16;
        f32x4 acc = {0.f, 0.f, 0.f, 0.f};
#pragma unroll
        for (int ks = 0; ks < 4; ks++) {
            bf16x8 bh = *(const bf16x8*)(WsH + n * Dd + ks * 32 + quad * 8);
            acc = __builtin_amdgcn_mfma_f32_16x16x32_bf16(ah[ks], bh, acc, 0, 0, 0);
            if (!BF) {
                bf16x8 bl = *(const bf16x8*)(WsL + n * Dd + ks * 32 + quad * 8);
                acc = __builtin_amdgcn_mfma_f32_16x16x32_bf16(al[ks], bh, acc, 0, 0, 0);
                acc = __builtin_amdgcn_mfma_f32_16x16x32_bf16(ah[ks], bl, acc, 0, 0, 0);
            }
        }
#pragma unroll
        for (int r = 0; r < 4; r++)
            hs[(size_t)(base + quad * 4 + r) * Dd + n] = f2bf(acc[r]);
    }
}
__global__ __launch_bounds__(256, 4) void k_hs(const void* hidden, const u16* WsH,
                                               const u16* WsL, u16* hs, const int* flag) {
    __shared__ __align__(16) u16 SL[4][SLAB];
    u16* slab = SL[threadIdx.x >> 6];
    if (*flag) hs_body<true>(hidden, WsH, WsL, hs, slab);
    else       hs_body<false>(hidden, WsH, WsL, hs, slab);
}

// ---------- counting-sort scatter ----------
__global__ __launch_bounds__(256) void k_scatter(const int* __restrict__ edges,
                                                 u32* __restrict__ slots,
                                                 int* __restrict__ deg, int nE) {
    int i = blockIdx.x * 256 + threadIdx.x;
    if (i >= nE) return;
    int bat = edges[4*i], sub = edges[4*i+1], rel = edges[4*i+2], obj = edges[4*i+3];
    int pos = atomicAdd(&deg[obj], 1);
    if (pos < MAXDEG)
        slots[obj * MAXDEG + pos] = (u32)sub | ((u32)rel << 18) | ((u32)bat << 26);
}

// ---------- fused: gather+alpha+aggregate -> slab -> 2-layer MFMA MLP ----------
template<bool BF>
__device__ __forceinline__ void edge_msg(u32 rec, int lane, float2 wa,
                                         const u16* hs, const float* wrq,
                                         const void* hidden, const float* relaf,
                                         float& a0, float& a1) {
    int sub = rec & 0x3FFFF, rel = (rec >> 18) & 0xFF, bat = (int)(rec >> 26);
    u32 hp = ((const u32*)hs)[sub * 64 + lane];
    float2 wq = ((const float2*)wrq)[(bat * Rr + rel) * 64 + lane];
    float mh0, mh1;
    if (BF) { u32 mh = ((const u32*)hidden)[sub * 64 + lane]; mh0 = bflo(mh); mh1 = bfhi(mh); }
    else    { float2 mh = ((const float2*)hidden)[sub * 64 + lane]; mh0 = mh.x; mh1 = mh.y; }
    float2 mr = ((const float2*)relaf)[rel * 64 + lane];
    float h0 = fmaxf(bflo(hp) + wq.x, 0.f);
    float h1 = fmaxf(bfhi(hp) + wq.y, 0.f);
    float p = h0 * wa.x + h1 * wa.y;
#pragma unroll
    for (int m = 32; m >= 1; m >>= 1) p += __shfl_xor(p, m);
    float alpha = 1.f / (1.f + __expf(-p));
    a0 += mh0 * mr.x * alpha;
    a1 += mh1 * mr.y * alpha;
}

template<bool BF>
__device__ void fused_body(const u32* __restrict__ slots, const int* __restrict__ deg,
                           const u16* __restrict__ hs, const float* __restrict__ wrq,
                           const float* __restrict__ wattnf,
                           const void* __restrict__ hidden, const float* __restrict__ relaf,
                           const u16* w1H, const u16* w1L, const u16* w2H, const u16* w2L,
                           const float* b1f, const float* b2f, void* out,
                           u16* __restrict__ Smh) {
    int t = threadIdx.x, w = t >> 6, lane = t & 63;
    int m16 = lane & 15, quad = lane >> 4;
    int base = blockIdx.x * 64 + w * 16;
    u16* Sml = Smh + 16 * LDW;
    float2 wa = ((const float2*)wattnf)[lane];

    // ---- gather phase: 16 nodes, wave-private, register accumulate ----
    for (int i = 0; i < 16; i++) {
        int node = base + i;
        int d = deg[node]; if (d > MAXDEG) d = MAXDEG;
        float a0 = 0.f, a1 = 0.f;
        float c0 = 0.f, c1 = 0.f;
        int e = 0;
        for (; e + 1 < d; e += 2) {   // 2-edge unroll for ILP
            u32 r0 = slots[node * MAXDEG + e];
            u32 r1 = slots[node * MAXDEG + e + 1];
            edge_msg<BF>(r0, lane, wa, hs, wrq, hidden, relaf, a0, a1);
            edge_msg<BF>(r1, lane, wa, hs, wrq, hidden, relaf, c0, c1);
        }
        if (e < d) {
            u32 r0 = slots[node * MAXDEG + e];
            edge_msg<BF>(r0, lane, wa, hs, wrq, hidden, relaf, a0, a1);
        }
        a0 += c0; a1 += c1;
        u16 h0 = f2bf(a0); u16 l0 = f2bf(a0 - bfs(h0));
        u16 h1 = f2bf(a1); u16 l1 = f2bf(a1 - bfs(h1));
        *(u32*)(Smh + i * LDW + 2 * lane) = (u32)h0 | ((u32)h1 << 16);
        *(u32*)(Sml + i * LDW + 2 * lane) = (u32)l0 | ((u32)l1 << 16);
    }

    // ---- layer 1: mid = agg @ W1^T + b1 (A-frags in regs, mid back to slab) ----
    const u16* ph = Smh + m16 * LDW + quad * 8;
    const u16* pl = Sml + m16 * LDW + quad * 8;
    bf16x8 ah[4], al[4];
#pragma unroll
    for (int ks = 0; ks < 4; ks++) {
        ah[ks] = *(const bf16x8*)(ph + ks * 32);
        al[ks] = *(const bf16x8*)(pl + ks * 32);
    }
#pragma unroll
    for (int nt = 0; nt < 8; nt++) {
        int n = nt * 16 + m16;
        f32x4 acc = {0.f, 0.f, 0.f, 0.f};
#pragma unroll
        for (int ks = 0; ks < 4; ks++) {
            bf16x8 bh = *(const bf16x8*)(w1H + n * Dd + ks * 32 + quad * 8);
            acc = __builtin_amdgcn_mfma_f32_16x16x32_bf16(ah[ks], bh, acc, 0, 0, 0);
            acc = __builtin_amdgcn_mfma_f32_16x16x32_bf16(al[ks], bh, acc, 0, 0, 0);
            if (!BF) {
                bf16x8 bl = *(const bf16x8*)(w1L + n * Dd + ks * 32 + quad * 8);
                acc = __builtin_amdgcn_mfma_f32_16x16x32_bf16(ah[ks], bl, acc, 0, 0, 0);
            }
        }
        float bv = b1f[n];
#pragma unroll
        for (int r = 0; r < 4; r++) {
            float v = acc[r] + bv;
            int row = quad * 4 + r;          // wave-private rows; frags already in regs
            u16 h = f2bf(v);
            Smh[row * LDW + n] = h;
            Sml[row * LDW + n] = f2bf(v - bfs(h));
        }
    }

    // ---- layer 2: out = relu(mid @ W2^T + b2), masked by deg ----
    bf16x8 mh[4], ml[4];
#pragma unroll
    for (int ks = 0; ks < 4; ks++) {
        mh[ks] = *(const bf16x8*)(ph + ks * 32);
        ml[ks] = *(const bf16x8*)(pl + ks * 32);
    }
    int dg[4];
#pragma unroll
    for (int r = 0; r < 4; r++) dg[r] = deg[base + quad * 4 + r];
#pragma unroll
    for (int nt = 0; nt < 8; nt++) {
        int n = nt * 16 + m16;
        f32x4 acc = {0.f, 0.f, 0.f, 0.f};
#pragma unroll
        for (int ks = 0; ks < 4; ks++) {
            bf16x8 bh = *(const bf16x8*)(w2H + n * Dd + ks * 32 + quad * 8);
            acc = __builtin_amdgcn_mfma_f32_16x16x32_bf16(mh[ks], bh, acc, 0, 0, 0);
            acc = __builtin_amdgcn_mfma_f32_16x16x32_bf16(ml[ks], bh, acc, 0, 0, 0);
            if (!BF) {
                bf16x8 bl = *(const bf16x8*)(w2L + n * Dd + ks * 32 + quad * 8);
                acc = __builtin_amdgcn_mfma_f32_16x16x32_bf16(mh[ks], bl, acc, 0, 0, 0);
            }
        }
        float bv = b2f[n];
#pragma unroll
        for (int r = 0; r < 4; r++) {
            float v = fmaxf(acc[r] + bv, 0.f);
            if (dg[r] == 0) v = 0.f;
            size_t o = (size_t)(base + quad * 4 + r) * Dd + n;
            if (BF) ((u16*)out)[o] = f2bf(v);
            else    ((float*)out)[o] = v;
        }
    }
}
__global__ __launch_bounds__(256, 4) void k_fused(const u32* slots, const int* deg,
                                                  const u16* hs, const float* wrq,
                                                  const float* wattnf, const void* hidden,
                                                  const float* relaf,
                                                  const u16* w1H, const u16* w1L,
                                                  const u16* w2H, const u16* w2L,
                                                  const float* b1f, const float* b2f,
                                                  void* out, const int* flag) {
    __shared__ __align__(16) u16 SL[4][SLAB];
    u16* slab = SL[threadIdx.x >> 6];
    if (*flag) fused_body<true>(slots, deg, hs, wrq, wattnf, hidden, relaf,
                                w1H, w1L, w2H, w2L, b1f, b2f, out, slab);
    else       fused_body<false>(slots, deg, hs, wrq, wattnf, hidden, relaf,
                                 w1H, w1L, w2H, w2L, b1f, b2f, out, slab);
}

extern "C" void kernel_launch(void* const* d_in, const int* in_sizes, int n_in,
                              void* d_out, int out_size, void* d_ws, size_t ws_size,
                              hipStream_t stream) {
    const void* query  = d_in[0];
    const void* hidden = d_in[3];
    const int*  edges  = (const int*)d_in[4];
    const void* Ws     = d_in[6];
    const void* Wr     = d_in[7];
    const void* Wqr    = d_in[8];
    const void* Wqrb   = d_in[9];
    const void* Wattn  = d_in[10];
    const void* rela   = d_in[11];
    const void* w1     = d_in[12];
    const void* b1     = d_in[13];
    const void* w2     = d_in[14];
    const void* b2     = d_in[15];

    char* ws = (char*)d_ws;
    u16*   hs     = (u16*)ws;                        //  51,200,000 B
    float* wrq    = (float*)(ws +  51200000);        //     409,600 B
    u32*   slots  = (u32*) (ws +  51609600);         //  25,600,000 B
    int*   deg    = (int*) (ws +  77209600);         //     800,000 B
    u16*   WsH    = (u16*) (ws +  78009600);
    u16*   WsL    = (u16*) (ws +  78042368);
    u16*   w1H    = (u16*) (ws +  78075136);
    u16*   w1L    = (u16*) (ws +  78107904);
    u16*   w2H    = (u16*) (ws +  78140672);
    u16*   w2L    = (u16*) (ws +  78173440);
    float* b1f    = (float*)(ws +  78206208);
    float* b2f    = (float*)(ws +  78206720);
    float* wattnf = (float*)(ws +  78207232);
    float* relaf  = (float*)(ws +  78207744);        //     102,400 B
    int*   flag   = (int*) (ws +  78310144);

    int nE = in_sizes[4] / 4;

    k_probe<<<1, 64, 0, stream>>>((const u32*)query, flag);
    hipMemsetAsync(deg, 0, (size_t)BN * 4, stream);
    k_wprep<<<294, 256, 0, stream>>>(Ws, w1, w2, b1, b2, Wattn, rela,
                                     WsH, WsL, w1H, w1L, w2H, w2L,
                                     b1f, b2f, wattnf, relaf, flag);
    k_wrq<<<Bb * Rr, 128, 0, stream>>>(Wr, Wqr, Wqrb, rela, query, wrq, flag);
    k_hs<<<BN / 64, 256, 0, stream>>>(hidden, WsH, WsL, hs, flag);
    k_scatter<<<(nE + 255) / 256, 256, 0, stream>>>(edges, slots, deg, nE);
    k_fused<<<BN / 64, 256, 0, stream>>>(slots, deg, hs, wrq, wattnf, hidden, relaf,
                                         w1H, w1L, w2H, w2L, b1f, b2f, d_out, flag);
}

// Round 3
// 676.092 us; speedup vs baseline: 1.1687x; 1.0136x over previous
//
#include <hip/hip_runtime.h>

typedef unsigned int u32;
typedef unsigned short u16;
typedef __attribute__((ext_vector_type(8))) short bf16x8;
typedef __attribute__((ext_vector_type(4))) float f32x4;

#define Bb 4
#define Nn 50000
#define Dd 128
#define Rr 200
#define BN (Bb*Nn)
#define MAXDEG 32
#define LDW 136          // u16 row stride inside a wave slab (272 B, 16B-aligned)
#define SLAB 4352        // u16 per wave slab: 2 tiles x 16 rows x 136

// ---------- scalar helpers ----------
__device__ __forceinline__ float bfs(u16 u) { return __uint_as_float(((u32)u) << 16); }
__device__ __forceinline__ float bflo(u32 u) { return __uint_as_float(u << 16); }
__device__ __forceinline__ float bfhi(u32 u) { return __uint_as_float(u & 0xffff0000u); }
__device__ __forceinline__ u16 f2bf(float f) {
    u32 x = __float_as_uint(f);
    return (u16)((x + 0x7fffu + ((x >> 16) & 1u)) >> 16);
}
template<bool BF>
__device__ __forceinline__ float ld1(const void* p, int i) {
    if (BF) return bfs(((const u16*)p)[i]);
    else    return ((const float*)p)[i];
}

// ---------- dtype probe: bf16-packed vs f32 ----------
__global__ void k_probe(const u32* __restrict__ q, int* __restrict__ flag) {
    int t = threadIdx.x;
    u32 w = q[t];
    int e = (int)((w >> 7) & 0xffu);
    bool plaus = (e >= 100 && e <= 150);
    unsigned long long m = __ballot(plaus);
    if (t == 0) flag[0] = (__popcll(m) >= 56) ? 1 : 0;
}

// ---------- prep: split weights to bf16 hi/lo, f32 copies of small tensors ----------
__global__ __launch_bounds__(256) void k_wprep(
    const void* Ws, const void* w1, const void* w2,
    const void* b1, const void* b2, const void* wattn, const void* rela,
    u16* WsH, u16* WsL, u16* w1H, u16* w1L, u16* w2H, u16* w2L,
    float* b1f, float* b2f, float* wattnf, float* relaf, const int* flag) {
    bool bf = (*flag != 0);
    int i = blockIdx.x * 256 + threadIdx.x;
    if (i < 16384) {
        float x = bf ? bfs(((const u16*)Ws)[i]) : ((const float*)Ws)[i];
        u16 h = f2bf(x); WsH[i] = h; WsL[i] = f2bf(x - bfs(h));
    } else if (i < 32768) {
        int j = i - 16384;
        float x = bf ? bfs(((const u16*)w1)[j]) : ((const float*)w1)[j];
        u16 h = f2bf(x); w1H[j] = h; w1L[j] = f2bf(x - bfs(h));
    } else if (i < 49152) {
        int j = i - 32768;
        float x = bf ? bfs(((const u16*)w2)[j]) : ((const float*)w2)[j];
        u16 h = f2bf(x); w2H[j] = h; w2L[j] = f2bf(x - bfs(h));
    } else if (i < 49152 + 128) {
        int j = i - 49152;
        b1f[j] = bf ? bfs(((const u16*)b1)[j]) : ((const float*)b1)[j];
    } else if (i < 49152 + 256) {
        int j = i - 49152 - 128;
        b2f[j] = bf ? bfs(((const u16*)b2)[j]) : ((const float*)b2)[j];
    } else if (i < 49152 + 384) {
        int j = i - 49152 - 256;
        wattnf[j] = bf ? bfs(((const u16*)wattn)[j]) : ((const float*)wattn)[j];
    } else if (i < 49152 + 384 + 25600) {
        int j = i - 49152 - 384;
        relaf[j] = bf ? bfs(((const u16*)rela)[j]) : ((const float*)rela)[j];
    }
}

// ---------- wrq[b*R+r][a] = Wr.rela_r + Wqr.query_b + bias (tiny, f32 VALU) ----------
template<bool BF>
__device__ __forceinline__ float dotrow1(const void* W, int row, const float* s) {
    float acc = 0.f;
    if (BF) {
        const uint4* wv = (const uint4*)((const u16*)W + row * Dd);
#pragma unroll
        for (int k = 0; k < 16; k++) {
            uint4 u = wv[k];
            acc += bflo(u.x)*s[k*8+0] + bfhi(u.x)*s[k*8+1]
                 + bflo(u.y)*s[k*8+2] + bfhi(u.y)*s[k*8+3]
                 + bflo(u.z)*s[k*8+4] + bfhi(u.z)*s[k*8+5]
                 + bflo(u.w)*s[k*8+6] + bfhi(u.w)*s[k*8+7];
        }
    } else {
        const float4* wv = (const float4*)((const float*)W + row * Dd);
#pragma unroll
        for (int k = 0; k < 32; k++) {
            float4 u = wv[k];
            acc += u.x*s[4*k] + u.y*s[4*k+1] + u.z*s[4*k+2] + u.w*s[4*k+3];
        }
    }
    return acc;
}
template<bool BF>
__device__ void k_wrq_body(const void* Wr, const void* Wqr, const void* bias,
                           const void* rela, const void* query, float* wrq, float* s) {
    int br = blockIdx.x;
    int b = br / Rr, r = br % Rr;
    int a = threadIdx.x;
    s[a]      = ld1<BF>(rela,  r * Dd + a);
    s[Dd + a] = ld1<BF>(query, b * Dd + a);
    __syncthreads();
    wrq[br * Dd + a] = ld1<BF>(bias, a) + dotrow1<BF>(Wr, a, s) + dotrow1<BF>(Wqr, a, s + Dd);
}
__global__ __launch_bounds__(128) void k_wrq(const void* Wr, const void* Wqr, const void* bias,
                                             const void* rela, const void* query, float* wrq,
                                             const int* flag) {
    __shared__ float s[2 * Dd];
    if (*flag) k_wrq_body<true>(Wr, Wqr, bias, rela, query, wrq, s);
    else       k_wrq_body<false>(Wr, Wqr, bias, rela, query, wrq, s);
}

// ---------- hs = hidden @ Ws^T via split-bf16 MFMA (wave-private slab, no barriers) ----------
template<bool BF>
__device__ void hs_body(const void* hidden, const u16* WsH, const u16* WsL, u16* hs,
                        u16* __restrict__ Smh) {
    int t = threadIdx.x, lane = t & 63;
    int m16 = lane & 15, quad = lane >> 4;
    int w = t >> 6;
    int base = blockIdx.x * 64 + w * 16;
    u16* Sml = Smh + 16 * LDW;

    if (BF) {
        const u16* src = (const u16*)hidden + (size_t)base * Dd;
#pragma unroll
        for (int j = 0; j < 4; j++) {
            int flat = j * 64 + lane;            // 256 chunks of 8 u16
            int row = flat >> 4, c8 = (flat & 15) * 8;
            uint4 v = ((const uint4*)src)[flat];
            *(uint4*)(Smh + row * LDW + c8) = v;
        }
    } else {
        const float* src = (const float*)hidden + (size_t)base * Dd;
#pragma unroll
        for (int j = 0; j < 8; j++) {
            int flat = j * 64 + lane;            // 512 float4 chunks
            int row = flat >> 5, c4 = (flat & 31) * 4;
            float4 v = ((const float4*)src)[flat];
            u16 h0 = f2bf(v.x), h1 = f2bf(v.y), h2 = f2bf(v.z), h3 = f2bf(v.w);
            ushort4 hv; hv.x = h0; hv.y = h1; hv.z = h2; hv.w = h3;
            ushort4 lv; lv.x = f2bf(v.x - bfs(h0)); lv.y = f2bf(v.y - bfs(h1));
                        lv.z = f2bf(v.z - bfs(h2)); lv.w = f2bf(v.w - bfs(h3));
            *(ushort4*)(Smh + row * LDW + c4) = hv;
            *(ushort4*)(Sml + row * LDW + c4) = lv;
        }
    }
    const u16* ph = Smh + m16 * LDW + quad * 8;
    const u16* pl = Sml + m16 * LDW + quad * 8;
    bf16x8 ah[4], al[4];
#pragma unroll
    for (int ks = 0; ks < 4; ks++) {
        ah[ks] = *(const bf16x8*)(ph + ks * 32);
        if (!BF) al[ks] = *(const bf16x8*)(pl + ks * 32);
    }
#pragma unroll
    for (int nt = 0; nt < 8; nt++) {
        int n = nt * 16 + m16;
        f32x4 acc = {0.f, 0.f, 0.f, 0.f};
#pragma unroll
        for (int ks = 0; ks < 4; ks++) {
            bf16x8 bh = *(const bf16x8*)(WsH + n * Dd + ks * 32 + quad * 8);
            acc = __builtin_amdgcn_mfma_f32_16x16x32_bf16(ah[ks], bh, acc, 0, 0, 0);
            if (!BF) {
                bf16x8 bl = *(const bf16x8*)(WsL + n * Dd + ks * 32 + quad * 8);
                acc = __builtin_amdgcn_mfma_f32_16x16x32_bf16(al[ks], bh, acc, 0, 0, 0);
                acc = __builtin_amdgcn_mfma_f32_16x16x32_bf16(ah[ks], bl, acc, 0, 0, 0);
            }
        }
#pragma unroll
        for (int r = 0; r < 4; r++)
            hs[(size_t)(base + quad * 4 + r) * Dd + n] = f2bf(acc[r]);
    }
}
__global__ __launch_bounds__(256, 4) void k_hs(const void* hidden, const u16* WsH,
                                               const u16* WsL, u16* hs, const int* flag) {
    __shared__ __align__(16) u16 SL[4][SLAB];
    u16* slab = SL[threadIdx.x >> 6];
    if (*flag) hs_body<true>(hidden, WsH, WsL, hs, slab);
    else       hs_body<false>(hidden, WsH, WsL, hs, slab);
}

// ---------- counting-sort scatter ----------
__global__ __launch_bounds__(256) void k_scatter(const int* __restrict__ edges,
                                                 u32* __restrict__ slots,
                                                 int* __restrict__ deg, int nE) {
    int i = blockIdx.x * 256 + threadIdx.x;
    if (i >= nE) return;
    int bat = edges[4*i], sub = edges[4*i+1], rel = edges[4*i+2], obj = edges[4*i+3];
    int pos = atomicAdd(&deg[obj], 1);
    if (pos < MAXDEG)
        slots[obj * MAXDEG + pos] = (u32)sub | ((u32)rel << 18) | ((u32)bat << 26);
}

// ---------- fused: gather+alpha+aggregate -> slab -> 2-layer MFMA MLP ----------
template<bool BF>
__device__ __forceinline__ void edge_msg(u32 rec, int lane, float2 wa,
                                         const u16* hs, const float* wrq,
                                         const void* hidden, const float* relaf,
                                         float& a0, float& a1) {
    int sub = rec & 0x3FFFF, rel = (rec >> 18) & 0xFF, bat = (int)(rec >> 26);
    u32 hp = ((const u32*)hs)[sub * 64 + lane];
    float2 wq = ((const float2*)wrq)[(bat * Rr + rel) * 64 + lane];
    float mh0, mh1;
    if (BF) { u32 mh = ((const u32*)hidden)[sub * 64 + lane]; mh0 = bflo(mh); mh1 = bfhi(mh); }
    else    { float2 mh = ((const float2*)hidden)[sub * 64 + lane]; mh0 = mh.x; mh1 = mh.y; }
    float2 mr = ((const float2*)relaf)[rel * 64 + lane];
    float h0 = fmaxf(bflo(hp) + wq.x, 0.f);
    float h1 = fmaxf(bfhi(hp) + wq.y, 0.f);
    float p = h0 * wa.x + h1 * wa.y;
#pragma unroll
    for (int m = 32; m >= 1; m >>= 1) p += __shfl_xor(p, m);
    float alpha = 1.f / (1.f + __expf(-p));
    a0 += mh0 * mr.x * alpha;
    a1 += mh1 * mr.y * alpha;
}

template<bool BF>
__device__ void fused_body(const u32* __restrict__ slots, const int* __restrict__ deg,
                           const u16* __restrict__ hs, const float* __restrict__ wrq,
                           const float* __restrict__ wattnf,
                           const void* __restrict__ hidden, const float* __restrict__ relaf,
                           const u16* w1H, const u16* w1L, const u16* w2H, const u16* w2L,
                           const float* b1f, const float* b2f, void* out,
                           u16* __restrict__ Smh) {
    int t = threadIdx.x, w = t >> 6, lane = t & 63;
    int m16 = lane & 15, quad = lane >> 4;
    int base = blockIdx.x * 64 + w * 16;
    u16* Sml = Smh + 16 * LDW;
    float2 wa = ((const float2*)wattnf)[lane];

    // ---- gather phase: node pairs; joint 4-chain phase + per-node round-1 drains ----
    for (int i = 0; i < 16; i += 2) {
        int nA = base + i, nB = base + i + 1;
        int dA = deg[nA]; if (dA > MAXDEG) dA = MAXDEG;
        int dB = deg[nB]; if (dB > MAXDEG) dB = MAXDEG;
        const u32* sA = slots + (size_t)nA * MAXDEG;
        const u32* sB = slots + (size_t)nB * MAXDEG;
        float aA0 = 0.f, aA1 = 0.f, cA0 = 0.f, cA1 = 0.f;
        float aB0 = 0.f, aB1 = 0.f, cB0 = 0.f, cB1 = 0.f;
        int eA = 0, eB = 0;

        // joint phase: both nodes have >=2 edges left -> 4 independent chains
        while (eA + 1 < dA && eB + 1 < dB) {
            u32 rA0 = sA[eA], rA1 = sA[eA + 1];
            u32 rB0 = sB[eB], rB1 = sB[eB + 1];
            edge_msg<BF>(rA0, lane, wa, hs, wrq, hidden, relaf, aA0, aA1);
            edge_msg<BF>(rB0, lane, wa, hs, wrq, hidden, relaf, aB0, aB1);
            edge_msg<BF>(rA1, lane, wa, hs, wrq, hidden, relaf, cA0, cA1);
            edge_msg<BF>(rB1, lane, wa, hs, wrq, hidden, relaf, cB0, cB1);
            eA += 2; eB += 2;
        }
        // drain node A (round-1 structure)
        for (; eA + 1 < dA; eA += 2) {
            u32 r0 = sA[eA], r1 = sA[eA + 1];
            edge_msg<BF>(r0, lane, wa, hs, wrq, hidden, relaf, aA0, aA1);
            edge_msg<BF>(r1, lane, wa, hs, wrq, hidden, relaf, cA0, cA1);
        }
        if (eA < dA) {
            u32 r0 = sA[eA];
            edge_msg<BF>(r0, lane, wa, hs, wrq, hidden, relaf, aA0, aA1);
        }
        // drain node B (round-1 structure)
        for (; eB + 1 < dB; eB += 2) {
            u32 r0 = sB[eB], r1 = sB[eB + 1];
            edge_msg<BF>(r0, lane, wa, hs, wrq, hidden, relaf, aB0, aB1);
            edge_msg<BF>(r1, lane, wa, hs, wrq, hidden, relaf, cB0, cB1);
        }
        if (eB < dB) {
            u32 r0 = sB[eB];
            edge_msg<BF>(r0, lane, wa, hs, wrq, hidden, relaf, aB0, aB1);
        }

        aA0 += cA0; aA1 += cA1;
        aB0 += cB0; aB1 += cB1;
        u16 hA0 = f2bf(aA0), lA0 = f2bf(aA0 - bfs(hA0));
        u16 hA1 = f2bf(aA1), lA1 = f2bf(aA1 - bfs(hA1));
        *(u32*)(Smh + i * LDW + 2 * lane) = (u32)hA0 | ((u32)hA1 << 16);
        *(u32*)(Sml + i * LDW + 2 * lane) = (u32)lA0 | ((u32)lA1 << 16);
        u16 hB0 = f2bf(aB0), lB0 = f2bf(aB0 - bfs(hB0));
        u16 hB1 = f2bf(aB1), lB1 = f2bf(aB1 - bfs(hB1));
        *(u32*)(Smh + (i + 1) * LDW + 2 * lane) = (u32)hB0 | ((u32)hB1 << 16);
        *(u32*)(Sml + (i + 1) * LDW + 2 * lane) = (u32)lB0 | ((u32)lB1 << 16);
    }

    // ---- layer 1: mid = agg @ W1^T + b1 (A-frags in regs, mid back to slab) ----
    const u16* ph = Smh + m16 * LDW + quad * 8;
    const u16* pl = Sml + m16 * LDW + quad * 8;
    bf16x8 ah[4], al[4];
#pragma unroll
    for (int ks = 0; ks < 4; ks++) {
        ah[ks] = *(const bf16x8*)(ph + ks * 32);
        al[ks] = *(const bf16x8*)(pl + ks * 32);
    }
#pragma unroll
    for (int nt = 0; nt < 8; nt++) {
        int n = nt * 16 + m16;
        f32x4 acc = {0.f, 0.f, 0.f, 0.f};
#pragma unroll
        for (int ks = 0; ks < 4; ks++) {
            bf16x8 bh = *(const bf16x8*)(w1H + n * Dd + ks * 32 + quad * 8);
            acc = __builtin_amdgcn_mfma_f32_16x16x32_bf16(ah[ks], bh, acc, 0, 0, 0);
            acc = __builtin_amdgcn_mfma_f32_16x16x32_bf16(al[ks], bh, acc, 0, 0, 0);
            if (!BF) {
                bf16x8 bl = *(const bf16x8*)(w1L + n * Dd + ks * 32 + quad * 8);
                acc = __builtin_amdgcn_mfma_f32_16x16x32_bf16(ah[ks], bl, acc, 0, 0, 0);
            }
        }
        float bv = b1f[n];
#pragma unroll
        for (int r = 0; r < 4; r++) {
            float v = acc[r] + bv;
            int row = quad * 4 + r;
            u16 h = f2bf(v);
            Smh[row * LDW + n] = h;
            Sml[row * LDW + n] = f2bf(v - bfs(h));
        }
    }

    // ---- layer 2: out = relu(mid @ W2^T + b2), masked by deg ----
    bf16x8 mh[4], ml[4];
#pragma unroll
    for (int ks = 0; ks < 4; ks++) {
        mh[ks] = *(const bf16x8*)(ph + ks * 32);
        ml[ks] = *(const bf16x8*)(pl + ks * 32);
    }
    int dg[4];
#pragma unroll
    for (int r = 0; r < 4; r++) dg[r] = deg[base + quad * 4 + r];
#pragma unroll
    for (int nt = 0; nt < 8; nt++) {
        int n = nt * 16 + m16;
        f32x4 acc = {0.f, 0.f, 0.f, 0.f};
#pragma unroll
        for (int ks = 0; ks < 4; ks++) {
            bf16x8 bh = *(const bf16x8*)(w2H + n * Dd + ks * 32 + quad * 8);
            acc = __builtin_amdgcn_mfma_f32_16x16x32_bf16(mh[ks], bh, acc, 0, 0, 0);
            acc = __builtin_amdgcn_mfma_f32_16x16x32_bf16(ml[ks], bh, acc, 0, 0, 0);
            if (!BF) {
                bf16x8 bl = *(const bf16x8*)(w2L + n * Dd + ks * 32 + quad * 8);
                acc = __builtin_amdgcn_mfma_f32_16x16x32_bf16(mh[ks], bl, acc, 0, 0, 0);
            }
        }
        float bv = b2f[n];
#pragma unroll
        for (int r = 0; r < 4; r++) {
            float v = fmaxf(acc[r] + bv, 0.f);
            if (dg[r] == 0) v = 0.f;
            size_t o = (size_t)(base + quad * 4 + r) * Dd + n;
            if (BF) ((u16*)out)[o] = f2bf(v);
            else    ((float*)out)[o] = v;
        }
    }
}
__global__ __launch_bounds__(256, 4) void k_fused(const u32* slots, const int* deg,
                                                  const u16* hs, const float* wrq,
                                                  const float* wattnf, const void* hidden,
                                                  const float* relaf,
                                                  const u16* w1H, const u16* w1L,
                                                  const u16* w2H, const u16* w2L,
                                                  const float* b1f, const float* b2f,
                                                  void* out, const int* flag) {
    __shared__ __align__(16) u16 SL[4][SLAB];
    u16* slab = SL[threadIdx.x >> 6];
    if (*flag) fused_body<true>(slots, deg, hs, wrq, wattnf, hidden, relaf,
                                w1H, w1L, w2H, w2L, b1f, b2f, out, slab);
    else       fused_body<false>(slots, deg, hs, wrq, wattnf, hidden, relaf,
                                 w1H, w1L, w2H, w2L, b1f, b2f, out, slab);
}

extern "C" void kernel_launch(void* const* d_in, const int* in_sizes, int n_in,
                              void* d_out, int out_size, void* d_ws, size_t ws_size,
                              hipStream_t stream) {
    const void* query  = d_in[0];
    const void* hidden = d_in[3];
    const int*  edges  = (const int*)d_in[4];
    const void* Ws     = d_in[6];
    const void* Wr     = d_in[7];
    const void* Wqr    = d_in[8];
    const void* Wqrb   = d_in[9];
    const void* Wattn  = d_in[10];
    const void* rela   = d_in[11];
    const void* w1     = d_in[12];
    const void* b1     = d_in[13];
    const void* w2     = d_in[14];
    const void* b2     = d_in[15];

    char* ws = (char*)d_ws;
    u16*   hs     = (u16*)ws;                        //  51,200,000 B
    float* wrq    = (float*)(ws +  51200000);        //     409,600 B
    u32*   slots  = (u32*) (ws +  51609600);         //  25,600,000 B
    int*   deg    = (int*) (ws +  77209600);         //     800,000 B
    u16*   WsH    = (u16*) (ws +  78009600);
    u16*   WsL    = (u16*) (ws +  78042368);
    u16*   w1H    = (u16*) (ws +  78075136);
    u16*   w1L    = (u16*) (ws +  78107904);
    u16*   w2H    = (u16*) (ws +  78140672);
    u16*   w2L    = (u16*) (ws +  78173440);
    float* b1f    = (float*)(ws +  78206208);
    float* b2f    = (float*)(ws +  78206720);
    float* wattnf = (float*)(ws +  78207232);
    float* relaf  = (float*)(ws +  78207744);        //     102,400 B
    int*   flag   = (int*) (ws +  78310144);

    int nE = in_sizes[4] / 4;

    k_probe<<<1, 64, 0, stream>>>((const u32*)query, flag);
    hipMemsetAsync(deg, 0, (size_t)BN * 4, stream);
    k_wprep<<<294, 256, 0, stream>>>(Ws, w1, w2, b1, b2, Wattn, rela,
                                     WsH, WsL, w1H, w1L, w2H, w2L,
                                     b1f, b2f, wattnf, relaf, flag);
    k_wrq<<<Bb * Rr, 128, 0, stream>>>(Wr, Wqr, Wqrb, rela, query, wrq, flag);
    k_hs<<<BN / 64, 256, 0, stream>>>(hidden, WsH, WsL, hs, flag);
    k_scatter<<<(nE + 255) / 256, 256, 0, stream>>>(edges, slots, deg, nE);
    k_fused<<<BN / 64, 256, 0, stream>>>(slots, deg, hs, wrq, wattnf, hidden, relaf,
                                         w1H, w1L, w2H, w2L, b1f, b2f, d_out, flag);
}

// Round 4
// 666.573 us; speedup vs baseline: 1.1854x; 1.0143x over previous
//
#include <hip/hip_runtime.h>

typedef unsigned int u32;
typedef unsigned short u16;
typedef __attribute__((ext_vector_type(8))) short bf16x8;
typedef __attribute__((ext_vector_type(4))) float f32x4;

#define Bb 4
#define Nn 50000
#define Dd 128
#define Rr 200
#define BN (Bb*Nn)
#define MAXDEG 32
#define LDW 136          // u16 row stride inside a wave slab (272 B, 16B-aligned)
#define SLAB 4352        // u16 per wave slab: 2 tiles x 16 rows x 136

// ---------- scalar helpers ----------
__device__ __forceinline__ float bfs(u16 u) { return __uint_as_float(((u32)u) << 16); }
__device__ __forceinline__ float bflo(u32 u) { return __uint_as_float(u << 16); }
__device__ __forceinline__ float bfhi(u32 u) { return __uint_as_float(u & 0xffff0000u); }
__device__ __forceinline__ u16 f2bf(float f) {
    u32 x = __float_as_uint(f);
    return (u16)((x + 0x7fffu + ((x >> 16) & 1u)) >> 16);
}
template<bool BF>
__device__ __forceinline__ float ld1(const void* p, int i) {
    if (BF) return bfs(((const u16*)p)[i]);
    else    return ((const float*)p)[i];
}

// ---------- dtype probe: bf16-packed vs f32 ----------
__global__ void k_probe(const u32* __restrict__ q, int* __restrict__ flag) {
    int t = threadIdx.x;
    u32 w = q[t];
    int e = (int)((w >> 7) & 0xffu);
    bool plaus = (e >= 100 && e <= 150);
    unsigned long long m = __ballot(plaus);
    if (t == 0) flag[0] = (__popcll(m) >= 56) ? 1 : 0;
}

// ---------- prep: split weights to bf16 hi/lo, f32 copies of small tensors ----------
__global__ __launch_bounds__(256) void k_wprep(
    const void* Ws, const void* w1, const void* w2,
    const void* b1, const void* b2, const void* wattn, const void* rela,
    u16* WsH, u16* WsL, u16* w1H, u16* w1L, u16* w2H, u16* w2L,
    float* b1f, float* b2f, float* wattnf, float* relaf, const int* flag) {
    bool bf = (*flag != 0);
    int i = blockIdx.x * 256 + threadIdx.x;
    if (i < 16384) {
        float x = bf ? bfs(((const u16*)Ws)[i]) : ((const float*)Ws)[i];
        u16 h = f2bf(x); WsH[i] = h; WsL[i] = f2bf(x - bfs(h));
    } else if (i < 32768) {
        int j = i - 16384;
        float x = bf ? bfs(((const u16*)w1)[j]) : ((const float*)w1)[j];
        u16 h = f2bf(x); w1H[j] = h; w1L[j] = f2bf(x - bfs(h));
    } else if (i < 49152) {
        int j = i - 32768;
        float x = bf ? bfs(((const u16*)w2)[j]) : ((const float*)w2)[j];
        u16 h = f2bf(x); w2H[j] = h; w2L[j] = f2bf(x - bfs(h));
    } else if (i < 49152 + 128) {
        int j = i - 49152;
        b1f[j] = bf ? bfs(((const u16*)b1)[j]) : ((const float*)b1)[j];
    } else if (i < 49152 + 256) {
        int j = i - 49152 - 128;
        b2f[j] = bf ? bfs(((const u16*)b2)[j]) : ((const float*)b2)[j];
    } else if (i < 49152 + 384) {
        int j = i - 49152 - 256;
        wattnf[j] = bf ? bfs(((const u16*)wattn)[j]) : ((const float*)wattn)[j];
    } else if (i < 49152 + 384 + 25600) {
        int j = i - 49152 - 384;
        relaf[j] = bf ? bfs(((const u16*)rela)[j]) : ((const float*)rela)[j];
    }
}

// ---------- wrq[b*R+r][a] = Wr.rela_r + Wqr.query_b + bias (tiny, f32 VALU) ----------
template<bool BF>
__device__ __forceinline__ float dotrow1(const void* W, int row, const float* s) {
    float acc = 0.f;
    if (BF) {
        const uint4* wv = (const uint4*)((const u16*)W + row * Dd);
#pragma unroll
        for (int k = 0; k < 16; k++) {
            uint4 u = wv[k];
            acc += bflo(u.x)*s[k*8+0] + bfhi(u.x)*s[k*8+1]
                 + bflo(u.y)*s[k*8+2] + bfhi(u.y)*s[k*8+3]
                 + bflo(u.z)*s[k*8+4] + bfhi(u.z)*s[k*8+5]
                 + bflo(u.w)*s[k*8+6] + bfhi(u.w)*s[k*8+7];
        }
    } else {
        const float4* wv = (const float4*)((const float*)W + row * Dd);
#pragma unroll
        for (int k = 0; k < 32; k++) {
            float4 u = wv[k];
            acc += u.x*s[4*k] + u.y*s[4*k+1] + u.z*s[4*k+2] + u.w*s[4*k+3];
        }
    }
    return acc;
}
template<bool BF>
__device__ void k_wrq_body(const void* Wr, const void* Wqr, const void* bias,
                           const void* rela, const void* query, float* wrq, float* s) {
    int br = blockIdx.x;
    int b = br / Rr, r = br % Rr;
    int a = threadIdx.x;
    s[a]      = ld1<BF>(rela,  r * Dd + a);
    s[Dd + a] = ld1<BF>(query, b * Dd + a);
    __syncthreads();
    wrq[br * Dd + a] = ld1<BF>(bias, a) + dotrow1<BF>(Wr, a, s) + dotrow1<BF>(Wqr, a, s + Dd);
}
__global__ __launch_bounds__(128) void k_wrq(const void* Wr, const void* Wqr, const void* bias,
                                             const void* rela, const void* query, float* wrq,
                                             const int* flag) {
    __shared__ float s[2 * Dd];
    if (*flag) k_wrq_body<true>(Wr, Wqr, bias, rela, query, wrq, s);
    else       k_wrq_body<false>(Wr, Wqr, bias, rela, query, wrq, s);
}

// ---------- hs = hidden @ Ws^T via split-bf16 MFMA (wave-private slab, no barriers) ----------
template<bool BF>
__device__ void hs_body(const void* hidden, const u16* WsH, const u16* WsL, u16* hs,
                        u16* __restrict__ Smh) {
    int t = threadIdx.x, lane = t & 63;
    int m16 = lane & 15, quad = lane >> 4;
    int w = t >> 6;
    int base = blockIdx.x * 64 + w * 16;
    u16* Sml = Smh + 16 * LDW;

    if (BF) {
        const u16* src = (const u16*)hidden + (size_t)base * Dd;
#pragma unroll
        for (int j = 0; j < 4; j++) {
            int flat = j * 64 + lane;            // 256 chunks of 8 u16
            int row = flat >> 4, c8 = (flat & 15) * 8;
            uint4 v = ((const uint4*)src)[flat];
            *(uint4*)(Smh + row * LDW + c8) = v;
        }
    } else {
        const float* src = (const float*)hidden + (size_t)base * Dd;
#pragma unroll
        for (int j = 0; j < 8; j++) {
            int flat = j * 64 + lane;            // 512 float4 chunks
            int row = flat >> 5, c4 = (flat & 31) * 4;
            float4 v = ((const float4*)src)[flat];
            u16 h0 = f2bf(v.x), h1 = f2bf(v.y), h2 = f2bf(v.z), h3 = f2bf(v.w);
            ushort4 hv; hv.x = h0; hv.y = h1; hv.z = h2; hv.w = h3;
            ushort4 lv; lv.x = f2bf(v.x - bfs(h0)); lv.y = f2bf(v.y - bfs(h1));
                        lv.z = f2bf(v.z - bfs(h2)); lv.w = f2bf(v.w - bfs(h3));
            *(ushort4*)(Smh + row * LDW + c4) = hv;
            *(ushort4*)(Sml + row * LDW + c4) = lv;
        }
    }
    const u16* ph = Smh + m16 * LDW + quad * 8;
    const u16* pl = Sml + m16 * LDW + quad * 8;
    bf16x8 ah[4], al[4];
#pragma unroll
    for (int ks = 0; ks < 4; ks++) {
        ah[ks] = *(const bf16x8*)(ph + ks * 32);
        if (!BF) al[ks] = *(const bf16x8*)(pl + ks * 32);
    }
#pragma unroll
    for (int nt = 0; nt < 8; nt++) {
        int n = nt * 16 + m16;
        f32x4 acc = {0.f, 0.f, 0.f, 0.f};
#pragma unroll
        for (int ks = 0; ks < 4; ks++) {
            bf16x8 bh = *(const bf16x8*)(WsH + n * Dd + ks * 32 + quad * 8);
            acc = __builtin_amdgcn_mfma_f32_16x16x32_bf16(ah[ks], bh, acc, 0, 0, 0);
            if (!BF) {
                bf16x8 bl = *(const bf16x8*)(WsL + n * Dd + ks * 32 + quad * 8);
                acc = __builtin_amdgcn_mfma_f32_16x16x32_bf16(al[ks], bh, acc, 0, 0, 0);
                acc = __builtin_amdgcn_mfma_f32_16x16x32_bf16(ah[ks], bl, acc, 0, 0, 0);
            }
        }
#pragma unroll
        for (int r = 0; r < 4; r++)
            hs[(size_t)(base + quad * 4 + r) * Dd + n] = f2bf(acc[r]);
    }
}
__global__ __launch_bounds__(256, 4) void k_hs(const void* hidden, const u16* WsH,
                                               const u16* WsL, u16* hs, const int* flag) {
    __shared__ __align__(16) u16 SL[4][SLAB];
    u16* slab = SL[threadIdx.x >> 6];
    if (*flag) hs_body<true>(hidden, WsH, WsL, hs, slab);
    else       hs_body<false>(hidden, WsH, WsL, hs, slab);
}

// ---------- counting-sort scatter ----------
__global__ __launch_bounds__(256) void k_scatter(const int* __restrict__ edges,
                                                 u32* __restrict__ slots,
                                                 int* __restrict__ deg, int nE) {
    int i = blockIdx.x * 256 + threadIdx.x;
    if (i >= nE) return;
    int bat = edges[4*i], sub = edges[4*i+1], rel = edges[4*i+2], obj = edges[4*i+3];
    int pos = atomicAdd(&deg[obj], 1);
    if (pos < MAXDEG)
        slots[obj * MAXDEG + pos] = (u32)sub | ((u32)rel << 18) | ((u32)bat << 26);
}

// ---------- fused: gather+alpha+aggregate -> slab -> 2-layer MFMA MLP ----------
// edge_pre: the 4 gathers + per-lane partial attention dot for one edge.
// Cross-lane reduce is DEFERRED so multiple edges' butterflies can be fused
// (a single edge's 6-level shfl chain is serial; batching levels across edges
// lets the shfls pipeline).
template<bool BF>
__device__ __forceinline__ void edge_pre(u32 rec, int lane, float2 wa,
                                         const u16* __restrict__ hs,
                                         const float* __restrict__ wrq,
                                         const void* __restrict__ hidden,
                                         const float* __restrict__ relaf,
                                         float& p, float& x, float& y) {
    int sub = rec & 0x3FFFF, rel = (rec >> 18) & 0xFF, bat = (int)(rec >> 26);
    u32 hp = ((const u32*)hs)[sub * 64 + lane];
    float2 wq = ((const float2*)wrq)[(bat * Rr + rel) * 64 + lane];
    float mh0, mh1;
    if (BF) { u32 mh = ((const u32*)hidden)[sub * 64 + lane]; mh0 = bflo(mh); mh1 = bfhi(mh); }
    else    { float2 mh = ((const float2*)hidden)[sub * 64 + lane]; mh0 = mh.x; mh1 = mh.y; }
    float2 mr = ((const float2*)relaf)[rel * 64 + lane];
    float h0 = fmaxf(bflo(hp) + wq.x, 0.f);
    float h1 = fmaxf(bfhi(hp) + wq.y, 0.f);
    p = h0 * wa.x + h1 * wa.y;
    x = mh0 * mr.x;
    y = mh1 * mr.y;
}

__device__ __forceinline__ float sigm(float p) { return 1.f / (1.f + __expf(-p)); }

template<bool BF>
__device__ void fused_body(const u32* __restrict__ slots, const int* __restrict__ deg,
                           const u16* __restrict__ hs, const float* __restrict__ wrq,
                           const float* __restrict__ wattnf,
                           const void* __restrict__ hidden, const float* __restrict__ relaf,
                           const u16* w1H, const u16* w1L, const u16* w2H, const u16* w2L,
                           const float* b1f, const float* b2f, void* out,
                           u16* __restrict__ Smh) {
    int t = threadIdx.x, w = t >> 6, lane = t & 63;
    int m16 = lane & 15, quad = lane >> 4;
    int base = blockIdx.x * 64 + w * 16;
    u16* Sml = Smh + 16 * LDW;
    float2 wa = ((const float2*)wattnf)[lane];

    // ---- gather phase: node pairs; fused multi-edge butterflies ----
    for (int i = 0; i < 16; i += 2) {
        int nA = base + i, nB = base + i + 1;
        int dA = deg[nA]; if (dA > MAXDEG) dA = MAXDEG;
        int dB = deg[nB]; if (dB > MAXDEG) dB = MAXDEG;
        const u32* sA = slots + (size_t)nA * MAXDEG;
        const u32* sB = slots + (size_t)nB * MAXDEG;
        float aA0 = 0.f, aA1 = 0.f, cA0 = 0.f, cA1 = 0.f;
        float aB0 = 0.f, aB1 = 0.f, cB0 = 0.f, cB1 = 0.f;
        int eA = 0, eB = 0;

        // joint 4-wide: 2 edges from each node, one fused butterfly
        while (eA + 1 < dA && eB + 1 < dB) {
            u32 rA0 = sA[eA], rA1 = sA[eA + 1];
            u32 rB0 = sB[eB], rB1 = sB[eB + 1];
            float pA0, xA0, yA0, pA1, xA1, yA1;
            float pB0, xB0, yB0, pB1, xB1, yB1;
            edge_pre<BF>(rA0, lane, wa, hs, wrq, hidden, relaf, pA0, xA0, yA0);
            edge_pre<BF>(rB0, lane, wa, hs, wrq, hidden, relaf, pB0, xB0, yB0);
            edge_pre<BF>(rA1, lane, wa, hs, wrq, hidden, relaf, pA1, xA1, yA1);
            edge_pre<BF>(rB1, lane, wa, hs, wrq, hidden, relaf, pB1, xB1, yB1);
#pragma unroll
            for (int m = 32; m >= 1; m >>= 1) {
                float tA0 = __shfl_xor(pA0, m);
                float tB0 = __shfl_xor(pB0, m);
                float tA1 = __shfl_xor(pA1, m);
                float tB1 = __shfl_xor(pB1, m);
                pA0 += tA0; pB0 += tB0; pA1 += tA1; pB1 += tB1;
            }
            float lA0 = sigm(pA0), lB0 = sigm(pB0), lA1 = sigm(pA1), lB1 = sigm(pB1);
            aA0 += xA0 * lA0; aA1 += yA0 * lA0;
            cA0 += xA1 * lA1; cA1 += yA1 * lA1;
            aB0 += xB0 * lB0; aB1 += yB0 * lB0;
            cB0 += xB1 * lB1; cB1 += yB1 * lB1;
            eA += 2; eB += 2;
        }
        // paired drain: one edge from each node (catches deg=(odd,odd) leftovers)
        while (eA < dA && eB < dB) {
            u32 rA0 = sA[eA], rB0 = sB[eB];
            float pA0, xA0, yA0, pB0, xB0, yB0;
            edge_pre<BF>(rA0, lane, wa, hs, wrq, hidden, relaf, pA0, xA0, yA0);
            edge_pre<BF>(rB0, lane, wa, hs, wrq, hidden, relaf, pB0, xB0, yB0);
#pragma unroll
            for (int m = 32; m >= 1; m >>= 1) {
                float tA0 = __shfl_xor(pA0, m);
                float tB0 = __shfl_xor(pB0, m);
                pA0 += tA0; pB0 += tB0;
            }
            float lA0 = sigm(pA0), lB0 = sigm(pB0);
            aA0 += xA0 * lA0; aA1 += yA0 * lA0;
            aB0 += xB0 * lB0; aB1 += yB0 * lB0;
            eA++; eB++;
        }
        // node-A drain: 2-wide fused, then single
        while (eA + 1 < dA) {
            u32 r0 = sA[eA], r1 = sA[eA + 1];
            float p0, x0, y0, p1, x1, y1;
            edge_pre<BF>(r0, lane, wa, hs, wrq, hidden, relaf, p0, x0, y0);
            edge_pre<BF>(r1, lane, wa, hs, wrq, hidden, relaf, p1, x1, y1);
#pragma unroll
            for (int m = 32; m >= 1; m >>= 1) {
                float t0 = __shfl_xor(p0, m);
                float t1 = __shfl_xor(p1, m);
                p0 += t0; p1 += t1;
            }
            float l0 = sigm(p0), l1 = sigm(p1);
            aA0 += x0 * l0; aA1 += y0 * l0;
            cA0 += x1 * l1; cA1 += y1 * l1;
            eA += 2;
        }
        if (eA < dA) {
            u32 r0 = sA[eA];
            float p0, x0, y0;
            edge_pre<BF>(r0, lane, wa, hs, wrq, hidden, relaf, p0, x0, y0);
#pragma unroll
            for (int m = 32; m >= 1; m >>= 1) p0 += __shfl_xor(p0, m);
            float l0 = sigm(p0);
            aA0 += x0 * l0; aA1 += y0 * l0;
        }
        // node-B drain: 2-wide fused, then single
        while (eB + 1 < dB) {
            u32 r0 = sB[eB], r1 = sB[eB + 1];
            float p0, x0, y0, p1, x1, y1;
            edge_pre<BF>(r0, lane, wa, hs, wrq, hidden, relaf, p0, x0, y0);
            edge_pre<BF>(r1, lane, wa, hs, wrq, hidden, relaf, p1, x1, y1);
#pragma unroll
            for (int m = 32; m >= 1; m >>= 1) {
                float t0 = __shfl_xor(p0, m);
                float t1 = __shfl_xor(p1, m);
                p0 += t0; p1 += t1;
            }
            float l0 = sigm(p0), l1 = sigm(p1);
            aB0 += x0 * l0; aB1 += y0 * l0;
            cB0 += x1 * l1; cB1 += y1 * l1;
            eB += 2;
        }
        if (eB < dB) {
            u32 r0 = sB[eB];
            float p0, x0, y0;
            edge_pre<BF>(r0, lane, wa, hs, wrq, hidden, relaf, p0, x0, y0);
#pragma unroll
            for (int m = 32; m >= 1; m >>= 1) p0 += __shfl_xor(p0, m);
            float l0 = sigm(p0);
            aB0 += x0 * l0; aB1 += y0 * l0;
        }

        aA0 += cA0; aA1 += cA1;
        aB0 += cB0; aB1 += cB1;
        u16 hA0 = f2bf(aA0), lA0_ = f2bf(aA0 - bfs(hA0));
        u16 hA1 = f2bf(aA1), lA1_ = f2bf(aA1 - bfs(hA1));
        *(u32*)(Smh + i * LDW + 2 * lane) = (u32)hA0 | ((u32)hA1 << 16);
        *(u32*)(Sml + i * LDW + 2 * lane) = (u32)lA0_ | ((u32)lA1_ << 16);
        u16 hB0 = f2bf(aB0), lB0_ = f2bf(aB0 - bfs(hB0));
        u16 hB1 = f2bf(aB1), lB1_ = f2bf(aB1 - bfs(hB1));
        *(u32*)(Smh + (i + 1) * LDW + 2 * lane) = (u32)hB0 | ((u32)hB1 << 16);
        *(u32*)(Sml + (i + 1) * LDW + 2 * lane) = (u32)lB0_ | ((u32)lB1_ << 16);
    }

    // ---- layer 1: mid = agg @ W1^T + b1 (A-frags in regs, mid back to slab) ----
    const u16* ph = Smh + m16 * LDW + quad * 8;
    const u16* pl = Sml + m16 * LDW + quad * 8;
    bf16x8 ah[4], al[4];
#pragma unroll
    for (int ks = 0; ks < 4; ks++) {
        ah[ks] = *(const bf16x8*)(ph + ks * 32);
        al[ks] = *(const bf16x8*)(pl + ks * 32);
    }
#pragma unroll
    for (int nt = 0; nt < 8; nt++) {
        int n = nt * 16 + m16;
        f32x4 acc = {0.f, 0.f, 0.f, 0.f};
#pragma unroll
        for (int ks = 0; ks < 4; ks++) {
            bf16x8 bh = *(const bf16x8*)(w1H + n * Dd + ks * 32 + quad * 8);
            acc = __builtin_amdgcn_mfma_f32_16x16x32_bf16(ah[ks], bh, acc, 0, 0, 0);
            acc = __builtin_amdgcn_mfma_f32_16x16x32_bf16(al[ks], bh, acc, 0, 0, 0);
            if (!BF) {
                bf16x8 bl = *(const bf16x8*)(w1L + n * Dd + ks * 32 + quad * 8);
                acc = __builtin_amdgcn_mfma_f32_16x16x32_bf16(ah[ks], bl, acc, 0, 0, 0);
            }
        }
        float bv = b1f[n];
#pragma unroll
        for (int r = 0; r < 4; r++) {
            float v = acc[r] + bv;
            int row = quad * 4 + r;
            u16 h = f2bf(v);
            Smh[row * LDW + n] = h;
            Sml[row * LDW + n] = f2bf(v - bfs(h));
        }
    }

    // ---- layer 2: out = relu(mid @ W2^T + b2), masked by deg ----
    bf16x8 mh[4], ml[4];
#pragma unroll
    for (int ks = 0; ks < 4; ks++) {
        mh[ks] = *(const bf16x8*)(ph + ks * 32);
        ml[ks] = *(const bf16x8*)(pl + ks * 32);
    }
    int dg[4];
#pragma unroll
    for (int r = 0; r < 4; r++) dg[r] = deg[base + quad * 4 + r];
#pragma unroll
    for (int nt = 0; nt < 8; nt++) {
        int n = nt * 16 + m16;
        f32x4 acc = {0.f, 0.f, 0.f, 0.f};
#pragma unroll
        for (int ks = 0; ks < 4; ks++) {
            bf16x8 bh = *(const bf16x8*)(w2H + n * Dd + ks * 32 + quad * 8);
            acc = __builtin_amdgcn_mfma_f32_16x16x32_bf16(mh[ks], bh, acc, 0, 0, 0);
            acc = __builtin_amdgcn_mfma_f32_16x16x32_bf16(ml[ks], bh, acc, 0, 0, 0);
            if (!BF) {
                bf16x8 bl = *(const bf16x8*)(w2L + n * Dd + ks * 32 + quad * 8);
                acc = __builtin_amdgcn_mfma_f32_16x16x32_bf16(mh[ks], bl, acc, 0, 0, 0);
            }
        }
        float bv = b2f[n];
#pragma unroll
        for (int r = 0; r < 4; r++) {
            float v = fmaxf(acc[r] + bv, 0.f);
            if (dg[r] == 0) v = 0.f;
            size_t o = (size_t)(base + quad * 4 + r) * Dd + n;
            if (BF) ((u16*)out)[o] = f2bf(v);
            else    ((float*)out)[o] = v;
        }
    }
}
__global__ __launch_bounds__(256, 4) void k_fused(const u32* slots, const int* deg,
                                                  const u16* hs, const float* wrq,
                                                  const float* wattnf, const void* hidden,
                                                  const float* relaf,
                                                  const u16* w1H, const u16* w1L,
                                                  const u16* w2H, const u16* w2L,
                                                  const float* b1f, const float* b2f,
                                                  void* out, const int* flag) {
    __shared__ __align__(16) u16 SL[4][SLAB];
    u16* slab = SL[threadIdx.x >> 6];
    if (*flag) fused_body<true>(slots, deg, hs, wrq, wattnf, hidden, relaf,
                                w1H, w1L, w2H, w2L, b1f, b2f, out, slab);
    else       fused_body<false>(slots, deg, hs, wrq, wattnf, hidden, relaf,
                                 w1H, w1L, w2H, w2L, b1f, b2f, out, slab);
}

extern "C" void kernel_launch(void* const* d_in, const int* in_sizes, int n_in,
                              void* d_out, int out_size, void* d_ws, size_t ws_size,
                              hipStream_t stream) {
    const void* query  = d_in[0];
    const void* hidden = d_in[3];
    const int*  edges  = (const int*)d_in[4];
    const void* Ws     = d_in[6];
    const void* Wr     = d_in[7];
    const void* Wqr    = d_in[8];
    const void* Wqrb   = d_in[9];
    const void* Wattn  = d_in[10];
    const void* rela   = d_in[11];
    const void* w1     = d_in[12];
    const void* b1     = d_in[13];
    const void* w2     = d_in[14];
    const void* b2     = d_in[15];

    char* ws = (char*)d_ws;
    u16*   hs     = (u16*)ws;                        //  51,200,000 B
    float* wrq    = (float*)(ws +  51200000);        //     409,600 B
    u32*   slots  = (u32*) (ws +  51609600);         //  25,600,000 B
    int*   deg    = (int*) (ws +  77209600);         //     800,000 B
    u16*   WsH    = (u16*) (ws +  78009600);
    u16*   WsL    = (u16*) (ws +  78042368);
    u16*   w1H    = (u16*) (ws +  78075136);
    u16*   w1L    = (u16*) (ws +  78107904);
    u16*   w2H    = (u16*) (ws +  78140672);
    u16*   w2L    = (u16*) (ws +  78173440);
    float* b1f    = (float*)(ws +  78206208);
    float* b2f    = (float*)(ws +  78206720);
    float* wattnf = (float*)(ws +  78207232);
    float* relaf  = (float*)(ws +  78207744);        //     102,400 B
    int*   flag   = (int*) (ws +  78310144);

    int nE = in_sizes[4] / 4;

    k_probe<<<1, 64, 0, stream>>>((const u32*)query, flag);
    hipMemsetAsync(deg, 0, (size_t)BN * 4, stream);
    k_wprep<<<294, 256, 0, stream>>>(Ws, w1, w2, b1, b2, Wattn, rela,
                                     WsH, WsL, w1H, w1L, w2H, w2L,
                                     b1f, b2f, wattnf, relaf, flag);
    k_wrq<<<Bb * Rr, 128, 0, stream>>>(Wr, Wqr, Wqrb, rela, query, wrq, flag);
    k_hs<<<BN / 64, 256, 0, stream>>>(hidden, WsH, WsL, hs, flag);
    k_scatter<<<(nE + 255) / 256, 256, 0, stream>>>(edges, slots, deg, nE);
    k_fused<<<BN / 64, 256, 0, stream>>>(slots, deg, hs, wrq, wattnf, hidden, relaf,
                                         w1H, w1L, w2H, w2L, b1f, b2f, d_out, flag);
}